// Round 1
// 370.875 us; speedup vs baseline: 1.5901x; 1.5901x over previous
//
#include <hip/hip_runtime.h>

// SpecAdaConv2d via split-bf16 MFMA implicit GEMM.
// out[b,co,p] = sum_{ci,k} (alpha[b,ci]*w[co,ci,k]) * x[b,ci,p+shift(k)] + bias[co]
// fp32 -> (hi,lo) bf16 split on both w and x; 3 products hi*hi + hi*lo_x + lo_w*hi
// (lo*lo dropped, ~2^-18 rel). 16x16x32 bf16 MFMA; matrix floor ~56 us.
//
// R1 change vs 587us baseline: occupancy. Old: 54.8KB LDS -> 2 blocks/CU ->
// 2 waves/SIMD, everything latency-stalled (MfmaUtil 10.7%, Occ 11.8%).
// New: (a) hi/lo packed into one 72-ushort row ([32 hi][32 lo][8 pad]) ->
// LDS 48.96KB, same bank profile, b_lo = offset:64 read; (b) 512-thread
// blocks, 8 waves each owning 2 M-tiles x 4 N-tiles (same per-block work,
// same total ds_read count); (c) __launch_bounds__(512,4) caps VGPR at 128.
// -> 2 blocks x 8 waves = 16 waves/CU = 4 waves/SIMD (2x latency hiding).

typedef __attribute__((ext_vector_type(8))) short short8;
typedef __attribute__((ext_vector_type(4))) float float4v;

#define BB 8
#define CI_N 64
#define CO_N 64
#define HH 256
#define WW 256
#define TW 32
#define TH 8
#define HALO_W 34
#define HALO_H 10
#define HALO_PX (HALO_W * HALO_H)   // 340
#define RS 72                        // packed row: [32 hi][32 lo][8 pad] ushorts
#define HI_OFF 32                    // lo block starts 32 ushorts (64 B) into row

#define NFRAG (2 * 9 * 2 * 4 * 64 * 8)  // 73728 packed bf16 elems

__device__ __forceinline__ unsigned f2bf(float v) {
    unsigned u = __float_as_uint(v);
    return (u + 0x7FFFu + ((u >> 16) & 1u)) >> 16;   // RNE to bf16
}

__global__ void prepack_w(const float* __restrict__ w, ushort* __restrict__ wp) {
    int idx = blockIdx.x * 256 + threadIdx.x;
    if (idx >= NFRAG) return;
    int j     = idx & 7;
    int lane  = (idx >> 3) & 63;
    int mt    = (idx >> 9) & 3;
    int plane = (idx >> 11) & 1;
    int rest  = idx >> 12;            // chunk*9 + k, 0..17
    int k     = rest % 9;
    int chunk = rest / 9;
    int co = mt * 16 + (lane & 15);
    int ci = chunk * 32 + (lane >> 4) * 8 + j;
    float v = w[(co * CI_N + ci) * 9 + k];
    unsigned hi = f2bf(v);
    float fhi = __uint_as_float(hi << 16);
    unsigned lo = f2bf(v - fhi);
    wp[idx] = (ushort)(plane ? lo : hi);
}

__global__ __launch_bounds__(512, 4) void conv_mfma(
    const float* __restrict__ x,      // (B, CIN, H, W)
    const float* __restrict__ alpha,  // (B, CIN)
    const ushort* __restrict__ wp,    // packed weights (d_ws)
    const float* __restrict__ bias,   // (COUT)
    float* __restrict__ out)          // (B, COUT, H, W)
{
    __shared__ __align__(16) ushort sx[HALO_PX * RS];  // 48960 B

    const int tid    = threadIdx.x;
    const int lane   = tid & 63;
    const int w_id   = tid >> 6;        // wave 0..7
    const int n_lane = lane & 15;
    const int q      = lane >> 4;
    const int b      = blockIdx.z;
    const int gx0    = blockIdx.x * TW;
    const int gy0    = blockIdx.y * TH;
    const int m_half = w_id >> 2;       // owns M-tiles m_half*2 + {0,1}
    const int n_q    = w_id & 3;        // owns N-tiles n_q*4 + {0..3}

    // acc init = bias (C/D layout: col=lane&15 -> px, row=q*4+r -> co)
    float4v acc[2][4];
#pragma unroll
    for (int mt = 0; mt < 2; ++mt) {
        float4v bi;
#pragma unroll
        for (int r = 0; r < 4; ++r)
            bi[r] = bias[(m_half * 2 + mt) * 16 + q * 4 + r];
#pragma unroll
        for (int nt = 0; nt < 4; ++nt) acc[mt][nt] = bi;
    }

    const float* xb = x + (size_t)b * CI_N * HH * WW;
    // per-lane LDS base for B-frag reads (ushort units): folds n_q rows, n_lane, q
    const int vbase = (n_q * 2 * HALO_W + n_lane) * RS + q * 8;

    for (int chunk = 0; chunk < 2; ++chunk) {
        if (chunk) __syncthreads();   // LDS reuse fence

        // ---- stage: wave w handles ci-pairs w*4 + p*2 for p in {0,1} ----
#pragma unroll
        for (int p = 0; p < 2; ++p) {
            const int cl = w_id * 4 + p * 2;         // 0..30, even
            const int ci = chunk * 32 + cl;
            const float a0 = alpha[b * CI_N + ci];
            const float a1 = alpha[b * CI_N + ci + 1];
            const float* xp0 = xb + (size_t)ci * HH * WW;
            const float* xp1 = xp0 + HH * WW;
#pragma unroll
            for (int it = 0; it < 6; ++it) {
                int hp = it * 64 + lane;
                if (hp < HALO_PX) {
                    int hy = hp / HALO_W;
                    int hx = hp - hy * HALO_W;
                    int gy = gy0 - 1 + hy;
                    int gx = gx0 - 1 + hx;
                    bool ok = ((unsigned)gy < HH) & ((unsigned)gx < WW);
                    int gidx = gy * WW + gx;
                    float v0 = ok ? xp0[gidx] * a0 : 0.0f;
                    float v1 = ok ? xp1[gidx] * a1 : 0.0f;
                    unsigned h0 = f2bf(v0);
                    unsigned h1 = f2bf(v1);
                    float f0 = __uint_as_float(h0 << 16);
                    float f1 = __uint_as_float(h1 << 16);
                    unsigned l0 = f2bf(v0 - f0);
                    unsigned l1 = f2bf(v1 - f1);
                    *(unsigned*)&sx[hp * RS + cl]          = h0 | (h1 << 16);
                    *(unsigned*)&sx[hp * RS + HI_OFF + cl] = l0 | (l1 << 16);
                }
            }
        }
        __syncthreads();

        // ---- compute: 9 shifts x (hi*hi, lo_w*hi, hi*lo_x) over K=32 ci ----
#pragma unroll
        for (int k = 0; k < 9; ++k) {
            const int dy = k / 3 - 1;
            const int dx = k % 3 - 1;
            // A-frags: coalesced dwordx4 from packed layout (L2-resident)
            short8 a_hi[2], a_lo[2];
#pragma unroll
            for (int mt = 0; mt < 2; ++mt) {
                int fh = ((chunk * 9 + k) * 2 + 0) * 4 + (m_half * 2 + mt);
                int fl = ((chunk * 9 + k) * 2 + 1) * 4 + (m_half * 2 + mt);
                a_hi[mt] = *(const short8*)(wp + (size_t)(fh * 64 + lane) * 8);
                a_lo[mt] = *(const short8*)(wp + (size_t)(fl * 64 + lane) * 8);
            }
#pragma unroll
            for (int nt_i = 0; nt_i < 4; ++nt_i) {
                // halo px for this N-tile + shift; vbase carries n_q/n_lane/q
                const int off = ((nt_i >> 1) + 1 + dy) * HALO_W + 1 + (nt_i & 1) * 16 + dx;
                const ushort* bp = &sx[vbase + off * RS];
                short8 b_hi = *(const short8*)bp;            // hi block
                short8 b_lo = *(const short8*)(bp + HI_OFF); // lo block, offset:64
                acc[0][nt_i] = __builtin_amdgcn_mfma_f32_16x16x32_bf16(a_hi[0], b_hi, acc[0][nt_i], 0, 0, 0);
                acc[1][nt_i] = __builtin_amdgcn_mfma_f32_16x16x32_bf16(a_hi[1], b_hi, acc[1][nt_i], 0, 0, 0);
                acc[0][nt_i] = __builtin_amdgcn_mfma_f32_16x16x32_bf16(a_lo[0], b_hi, acc[0][nt_i], 0, 0, 0);
                acc[1][nt_i] = __builtin_amdgcn_mfma_f32_16x16x32_bf16(a_lo[1], b_hi, acc[1][nt_i], 0, 0, 0);
                acc[0][nt_i] = __builtin_amdgcn_mfma_f32_16x16x32_bf16(a_hi[0], b_lo, acc[0][nt_i], 0, 0, 0);
                acc[1][nt_i] = __builtin_amdgcn_mfma_f32_16x16x32_bf16(a_hi[1], b_lo, acc[1][nt_i], 0, 0, 0);
            }
        }
    }

    // ---- epilogue: store (64B-segment coalescing: 16 px x 4 co groups) ----
#pragma unroll
    for (int mt = 0; mt < 2; ++mt) {
        const int m0 = (m_half * 2 + mt) * 16;
#pragma unroll
        for (int nt_i = 0; nt_i < 4; ++nt_i) {
            const int nt = n_q * 4 + nt_i;
            const int gy = gy0 + (nt >> 1);
            const int gx = gx0 + (nt & 1) * 16 + n_lane;
#pragma unroll
            for (int r = 0; r < 4; ++r) {
                const int co = m0 + q * 4 + r;
                out[(((size_t)b * CO_N + co) * HH + gy) * WW + gx] = acc[mt][nt_i][r];
            }
        }
    }
}

extern "C" void kernel_launch(void* const* d_in, const int* in_sizes, int n_in,
                              void* d_out, int out_size, void* d_ws, size_t ws_size,
                              hipStream_t stream) {
    const float* x     = (const float*)d_in[0];
    const float* alpha = (const float*)d_in[1];
    const float* w     = (const float*)d_in[2];
    const float* bias  = (const float*)d_in[3];
    float* out  = (float*)d_out;
    ushort* wpk = (ushort*)d_ws;

    prepack_w<<<dim3((NFRAG + 255) / 256), dim3(256), 0, stream>>>(w, wpk);

    dim3 grid(WW / TW, HH / TH, BB);   // (8, 32, 8) = 2048 blocks
    conv_mfma<<<grid, dim3(512), 0, stream>>>(x, alpha, wpk, bias, out);
}